// Round 1
// baseline (82.767 us; speedup 1.0000x reference)
//
#include <hip/hip_runtime.h>

// Temporal shift: x (N=16, C=256, T=16, H=28, W=28) fp32.
// fold = C/8 = 32:
//   c in [0,32):   y[t] = x[t+3]   (look ahead)
//   c in [32,64):  y[t] = x[t-3]   (look back)
//   c in [64,256): y[t] = x[t]     (identity)
// zero outside t-range. Pure memory-bound permuted copy.

constexpr int kN = 16, kC = 256, kT = 16, kHW = 28 * 28;   // 784
constexpr int kHW4 = kHW / 4;                              // 196 float4 per (n,c,t) row
constexpr int kTotal4 = kN * kC * kT * kHW4;               // 12,845,056 (< 2^31)

__global__ __launch_bounds__(256)
void tshift_kernel(const float4* __restrict__ x, float4* __restrict__ y) {
    const int stride = gridDim.x * blockDim.x;
    for (int i = blockIdx.x * blockDim.x + threadIdx.x; i < kTotal4; i += stride) {
        const int t = (i / kHW4) % kT;
        const int c = (i / (kHW4 * kT)) % kC;
        // fold boundaries hard-coded from the deterministic one-hot weight
        const int delta = (c < 32) ? 3 : ((c < 64) ? -3 : 0);
        const int ts = t + delta;
        float4 v = make_float4(0.f, 0.f, 0.f, 0.f);
        if ((unsigned)ts < (unsigned)kT) {
            v = x[i + delta * kHW4];
        }
        y[i] = v;
    }
}

extern "C" void kernel_launch(void* const* d_in, const int* in_sizes, int n_in,
                              void* d_out, int out_size, void* d_ws, size_t ws_size,
                              hipStream_t stream) {
    const float4* x = (const float4*)d_in[0];
    float4* y = (float4*)d_out;

    const int block = 256;
    // memory-bound: cap grid, grid-stride the rest (256 CU * 8 blocks)
    int grid = (kTotal4 + block - 1) / block;
    if (grid > 2048) grid = 2048;

    tshift_kernel<<<grid, block, 0, stream>>>(x, y);
}

// Round 3
// 62.334 us; speedup vs baseline: 1.3278x; 1.3278x over previous
//
#include <hip/hip_runtime.h>

// Temporal shift: x (N=16, C=256, T=16, H=28, W=28) fp32.
// fold = C/8 = 32:
//   c in [0,32):   y[t] = x[t+3]   (look ahead)
//   c in [32,64):  y[t] = x[t-3]   (look back)
//   c in [64,256): y[t] = x[t]     (identity)
// zero outside t-range. Pure memory-bound permuted copy.
//
// R3: same as R2 but with clang native vector type so
//     __builtin_nontemporal_store compiles (HIP float4 is a class -> rejected).

typedef float f32x4 __attribute__((ext_vector_type(4)));

constexpr int kC = 256, kT = 16;
constexpr int kHW4 = (28 * 28) / 4;                  // 196 float4 per (n,c,t) row
constexpr int kTotal4 = 16 * kC * kT * kHW4;         // 12,845,056
constexpr int kBlocks = 3584;                        // exact partition
constexpr int kIters = kTotal4 / (kBlocks * 256);    // = 14

static_assert(kBlocks * 256 * kIters == kTotal4, "partition must be exact");

__global__ __launch_bounds__(256)
void tshift_kernel(const f32x4* __restrict__ x, f32x4* __restrict__ y) {
    int i = blockIdx.x * 256 + threadIdx.x;
    constexpr int kStride = kBlocks * 256;
#pragma unroll
    for (int k = 0; k < kIters; ++k, i += kStride) {
        const int t = (i / kHW4) % kT;
        const int c = (i / (kHW4 * kT)) % kC;
        // fold boundaries hard-coded from the deterministic one-hot weight
        const int delta = (c < 32) ? 3 : ((c < 64) ? -3 : 0);
        const int ts = t + delta;
        f32x4 v = (f32x4)(0.f);
        if ((unsigned)ts < (unsigned)kT) {
            v = x[i + delta * kHW4];
        }
        __builtin_nontemporal_store(v, &y[i]);
    }
}

extern "C" void kernel_launch(void* const* d_in, const int* in_sizes, int n_in,
                              void* d_out, int out_size, void* d_ws, size_t ws_size,
                              hipStream_t stream) {
    const f32x4* x = (const f32x4*)d_in[0];
    f32x4* y = (f32x4*)d_out;
    tshift_kernel<<<kBlocks, 256, 0, stream>>>(x, y);
}

// Round 5
// 62.216 us; speedup vs baseline: 1.3303x; 1.0019x over previous
//
#include <hip/hip_runtime.h>

// Temporal shift: x (N=16, C=256, T=16, H=28, W=28) fp32.
// fold = C/8 = 32:
//   c in [0,32):   y[t] = x[t+3]   (look ahead)
//   c in [32,64):  y[t] = x[t-3]   (look back)
//   c in [64,256): y[t] = x[t]     (identity)
// zero outside t-range. Pure memory-bound permuted copy.
//
// R5: revert to R3 (known-good, 62.3us = 6.44 TB/s mixed r/w).
// R4's sc0/sc1/nt cache-bypass store broke coherence with the harness's
// readback (stale zero lines in MALL) -> outputs read back as zeros.
// MALL-residency play is structurally impossible anyway: input+output
// = 411MB > 256MB MALL and each input element is read exactly once.

typedef float f32x4 __attribute__((ext_vector_type(4)));

constexpr int kC = 256, kT = 16;
constexpr int kHW4 = (28 * 28) / 4;                  // 196 float4 per (n,c,t) row
constexpr int kTotal4 = 16 * kC * kT * kHW4;         // 12,845,056
constexpr int kBlocks = 3584;                        // exact partition
constexpr int kIters = kTotal4 / (kBlocks * 256);    // = 14

static_assert(kBlocks * 256 * kIters == kTotal4, "partition must be exact");

__global__ __launch_bounds__(256)
void tshift_kernel(const f32x4* __restrict__ x, f32x4* __restrict__ y) {
    int i = blockIdx.x * 256 + threadIdx.x;
    constexpr int kStride = kBlocks * 256;
#pragma unroll
    for (int k = 0; k < kIters; ++k, i += kStride) {
        const int t = (i / kHW4) % kT;
        const int c = (i / (kHW4 * kT)) % kC;
        // fold boundaries hard-coded from the deterministic one-hot weight
        const int delta = (c < 32) ? 3 : ((c < 64) ? -3 : 0);
        const int ts = t + delta;
        f32x4 v = (f32x4)(0.f);
        if ((unsigned)ts < (unsigned)kT) {
            v = x[i + delta * kHW4];
        }
        __builtin_nontemporal_store(v, &y[i]);
    }
}

extern "C" void kernel_launch(void* const* d_in, const int* in_sizes, int n_in,
                              void* d_out, int out_size, void* d_ws, size_t ws_size,
                              hipStream_t stream) {
    const f32x4* x = (const f32x4*)d_in[0];
    f32x4* y = (f32x4*)d_out;
    tshift_kernel<<<kBlocks, 256, 0, stream>>>(x, y);
}

// Round 6
// 61.948 us; speedup vs baseline: 1.3361x; 1.0043x over previous
//
#include <hip/hip_runtime.h>

// Temporal shift: x (N=16, C=256, T=16, H=28, W=28) fp32.
// fold = C/8 = 32:
//   c in [0,32):   y[t] = x[t+3]   (look ahead)
//   c in [32,64):  y[t] = x[t-3]   (look back)
//   c in [64,256): y[t] = x[t]     (identity)
// zero outside t-range. Pure memory-bound permuted copy.
//
// R6: R5 showed VGPR_Count=8 -> compiler emitted load/wait/store per iter,
// per-wave MLP=1 (latency-bound suspect). Restructure: 2 batches of 7
// {issue 7 loads -> 7 stores} for 7 outstanding loads/wave while staying
// under the 64-VGPR occupancy cliff (8 waves/SIMD preserved).

typedef float f32x4 __attribute__((ext_vector_type(4)));

constexpr int kC = 256, kT = 16;
constexpr int kHW4 = (28 * 28) / 4;                  // 196 float4 per (n,c,t) row
constexpr int kTotal4 = 16 * kC * kT * kHW4;         // 12,845,056
constexpr int kBlocks = 3584;                        // exact partition
constexpr int kIters = kTotal4 / (kBlocks * 256);    // = 14
constexpr int kBatch = 7;                            // loads in flight per wave

static_assert(kBlocks * 256 * kIters == kTotal4, "partition must be exact");
static_assert(kIters == 2 * kBatch, "two batches");

__global__ __launch_bounds__(256)
void tshift_kernel(const f32x4* __restrict__ x, f32x4* __restrict__ y) {
    const int base = blockIdx.x * 256 + threadIdx.x;
    constexpr int kStride = kBlocks * 256;
#pragma unroll
    for (int b = 0; b < 2; ++b) {
        f32x4 v[kBatch];           // fully unrolled -> static indices, stays in VGPRs
#pragma unroll
        for (int k = 0; k < kBatch; ++k) {
            const int i = base + (b * kBatch + k) * kStride;
            const int t = (i / kHW4) % kT;
            const int c = (i / (kHW4 * kT)) % kC;
            const int delta = (c < 32) ? 3 : ((c < 64) ? -3 : 0);
            const int ts = t + delta;
            v[k] = (f32x4)(0.f);
            if ((unsigned)ts < (unsigned)kT) {
                v[k] = x[i + delta * kHW4];
            }
        }
#pragma unroll
        for (int k = 0; k < kBatch; ++k) {
            const int i = base + (b * kBatch + k) * kStride;
            __builtin_nontemporal_store(v[k], &y[i]);
        }
    }
}

extern "C" void kernel_launch(void* const* d_in, const int* in_sizes, int n_in,
                              void* d_out, int out_size, void* d_ws, size_t ws_size,
                              hipStream_t stream) {
    const f32x4* x = (const f32x4*)d_in[0];
    f32x4* y = (f32x4*)d_out;
    tshift_kernel<<<kBlocks, 256, 0, stream>>>(x, y);
}